// Round 1
// baseline (579.323 us; speedup 1.0000x reference)
//
#include <hip/hip_runtime.h>
#include <cstdint>

#define K_NE 16
constexpr int B = 8, N = 2048, F = 128;
constexpr size_t NSEND = (size_t)B * N;                 // 16384 sender rows
constexpr size_t EDGE_FLOATS = NSEND * K_NE * 256;      // 67,108,864
constexpr size_t SEND_FLOATS = (size_t)B * N * N;       // 33,554,432

// ---------------- K0: row norms (one wave per 128-float row) ----------------
__global__ __launch_bounds__(256) void norms_kernel(const float* __restrict__ X,
                                                    float* __restrict__ out) {
    int tid = blockIdx.x * 256 + threadIdx.x;
    int w = tid >> 6, lane = tid & 63;
    const float2 v = ((const float2*)(X + (size_t)w * F))[lane];
    float s = v.x * v.x + v.y * v.y;
    #pragma unroll
    for (int off = 32; off; off >>= 1) s += __shfl_xor(s, off);
    if (lane == 0) out[w] = s;
}

// ---------------- K1: score matrix  dist[b][s][r] = |x2+y2-2*dot| -----------
// 64x64 tile, 4x4 register tile, K=128 fully staged in padded LDS.
__global__ __launch_bounds__(256) void score_kernel(const float* __restrict__ S,
                                                    const float* __restrict__ Rv,
                                                    const float* __restrict__ x2,
                                                    const float* __restrict__ y2,
                                                    float* __restrict__ scores) {
    __shared__ float As[64][132];   // pad 128->132 floats: +16B per row, bank-spread
    __shared__ float Bs[64][132];
    const int bx = blockIdx.x, by = blockIdx.y, bz = blockIdx.z;
    const int t = threadIdx.x;
    const float* Sb = S  + (size_t)bz * N * F + (size_t)by * 64 * F;
    const float* Rb = Rv + (size_t)bz * N * F + (size_t)bx * 64 * F;
    #pragma unroll
    for (int i = 0; i < 8; ++i) {
        int id = t + (i << 8);
        int row = id >> 5, c4 = (id & 31) << 2;
        *(float4*)(&As[row][c4]) = *(const float4*)(Sb + row * F + c4);
        *(float4*)(&Bs[row][c4]) = *(const float4*)(Rb + row * F + c4);
    }
    __syncthreads();
    const int tx = t & 15, ty = t >> 4;
    float acc[4][4] = {};
    #pragma unroll
    for (int k = 0; k < 32; ++k) {
        float4 av[4], bv[4];
        #pragma unroll
        for (int i = 0; i < 4; ++i) av[i] = *(const float4*)(&As[ty * 4 + i][k << 2]);
        #pragma unroll
        for (int j = 0; j < 4; ++j) bv[j] = *(const float4*)(&Bs[tx * 4 + j][k << 2]);
        #pragma unroll
        for (int i = 0; i < 4; ++i)
            #pragma unroll
            for (int j = 0; j < 4; ++j) {
                acc[i][j] = fmaf(av[i].x, bv[j].x, acc[i][j]);
                acc[i][j] = fmaf(av[i].y, bv[j].y, acc[i][j]);
                acc[i][j] = fmaf(av[i].z, bv[j].z, acc[i][j]);
                acc[i][j] = fmaf(av[i].w, bv[j].w, acc[i][j]);
            }
    }
    float* outb = scores + (size_t)bz * N * N;
    const float* x2b = x2 + (size_t)bz * N;
    const float* y2b = y2 + (size_t)bz * N;
    const int rcol = bx * 64 + tx * 4;
    float yv[4];
    #pragma unroll
    for (int j = 0; j < 4; ++j) yv[j] = y2b[rcol + j];
    #pragma unroll
    for (int i = 0; i < 4; ++i) {
        int srow = by * 64 + ty * 4 + i;
        float xv = x2b[srow];
        float4 o;
        // match reference order: (mixed + x2) + y2, mixed = -2*dot
        o.x = fabsf((-2.0f * acc[i][0] + xv) + yv[0]);
        o.y = fabsf((-2.0f * acc[i][1] + xv) + yv[1]);
        o.z = fabsf((-2.0f * acc[i][2] + xv) + yv[2]);
        o.w = fabsf((-2.0f * acc[i][3] + xv) + yv[3]);
        *(float4*)(outb + (size_t)srow * N + rcol) = o;
    }
}

// ---------------- K2: top-16 per sender row, ascending-index emit -----------
// One wave per row. Iterative lexicographic argmin x16 -> threshold T,
// then ballot-based ordered single pass (strict-less, equals capped by quota).
__global__ __launch_bounds__(256) void topk_kernel(const float* __restrict__ scores,
                                                   int* __restrict__ idxb) {
    const int t = threadIdx.x;
    const int lane = t & 63;
    const int row = blockIdx.x * 4 + (t >> 6);   // global sender id
    const float* sr = scores + (size_t)row * N;
    float c[32], w[32];
    #pragma unroll
    for (int j = 0; j < 32; ++j) { c[j] = sr[(j << 6) + lane]; w[j] = c[j]; }
    float T = 0.0f;
    for (int it = 0; it < 16; ++it) {
        float bv = w[0]; int bi = lane;
        #pragma unroll
        for (int j = 1; j < 32; ++j) {
            int idx = (j << 6) + lane;
            if (w[j] < bv) { bv = w[j]; bi = idx; }
        }
        #pragma unroll
        for (int off = 32; off; off >>= 1) {
            float ov = __shfl_xor(bv, off);
            int   oi = __shfl_xor(bi, off);
            if (ov < bv || (ov == bv && oi < bi)) { bv = ov; bi = oi; }
        }
        T = bv;
        int jj = bi >> 6;
        bool mine = (bi & 63) == lane;
        #pragma unroll
        for (int j = 0; j < 32; ++j)
            if (mine && jj == j) w[j] = __builtin_inff();
    }
    // m = count strictly below T (wave-uniform)
    int m = 0;
    #pragma unroll
    for (int j = 0; j < 32; ++j) m += __popcll(__ballot(c[j] < T));
    const int quota = K_NE - m;
    const unsigned long long lt = (1ull << lane) - 1ull;
    int emitted = 0, eqc = 0;
    int* ob = idxb + row * K_NE;
    #pragma unroll
    for (int j = 0; j < 32; ++j) {
        float v = c[j];
        int idx = (j << 6) + lane;
        unsigned long long em = __ballot(v == T);
        int eq_rank = eqc + __popcll(em & lt);
        bool acc = (v < T) || ((v == T) && (eq_rank < quota));
        unsigned long long am = __ballot(acc);
        if (acc) ob[emitted + __popcll(am & lt)] = idx;
        emitted += __popcll(am);
        eqc += __popcll(em);
    }
}

// ---------------- K3: edge rows (fully coalesced float4 writes) -------------
__global__ __launch_bounds__(256) void edges_kernel(const float* __restrict__ S,
                                                    const float* __restrict__ Rv,
                                                    const int* __restrict__ idxb,
                                                    float* __restrict__ out) {
    const int g = blockIdx.x;            // sender id 0..16383
    const int t = threadIdx.x;
    __shared__ int sidx[K_NE];
    if (t < K_NE) sidx[t] = idxb[g * K_NE + t];
    __syncthreads();
    const float4* srow = (const float4*)(S + (size_t)g * F);
    const float4* rb = (const float4*)(Rv + (size_t)(g >> 11) * N * F);
    float4* ob = (float4*)(out + (size_t)g * (K_NE * 256));
    #pragma unroll
    for (int i = 0; i < 4; ++i) {
        int f = t + (i << 8);            // float4 id within the 16x256 block
        int e = f >> 6, p = f & 63;
        float4 v = (p < 32) ? srow[p] : rb[(size_t)sidx[e] * 32 + (p - 32)];
        ob[f] = v;
    }
}

// ---------------- K4: scatter ones into zeroed connectivity matrix ----------
__global__ __launch_bounds__(256) void ones_kernel(const int* __restrict__ idxb,
                                                   float* __restrict__ sm) {
    int e = blockIdx.x * 256 + threadIdx.x;  // edge id 0..262143
    int g = e >> 4;
    int col = idxb[e];
    sm[(size_t)g * N + col] = 1.0f;
}

extern "C" void kernel_launch(void* const* d_in, const int* in_sizes, int n_in,
                              void* d_out, int out_size, void* d_ws, size_t ws_size,
                              hipStream_t stream) {
    (void)in_sizes; (void)n_in; (void)out_size;
    const float* recv = (const float*)d_in[0];
    const float* send = (const float*)d_in[1];
    float* out = (float*)d_out;
    float* sender_mat = out + EDGE_FLOATS;       // also used as 128MB score scratch
    // ws layout: idx [262144 int] @0, x2 [16384 f32] @1MB, y2 @1MB+64KB  (1.125MB)
    int*   idx_ws = (int*)d_ws;
    float* x2 = (float*)((char*)d_ws + (262144u * 4));
    float* y2 = x2 + NSEND;

    norms_kernel<<<4096, 256, 0, stream>>>(send, x2);
    norms_kernel<<<4096, 256, 0, stream>>>(recv, y2);
    dim3 g1(32, 32, 8);
    score_kernel<<<g1, 256, 0, stream>>>(send, recv, x2, y2, sender_mat);
    topk_kernel<<<4096, 256, 0, stream>>>(sender_mat, idx_ws);
    edges_kernel<<<16384, 256, 0, stream>>>(send, recv, idx_ws, out);
    hipMemsetAsync(sender_mat, 0, SEND_FLOATS * sizeof(float), stream);
    ones_kernel<<<1024, 256, 0, stream>>>(idx_ws, sender_mat);
}

// Round 2
// 303.877 us; speedup vs baseline: 1.9064x; 1.9064x over previous
//
#include <hip/hip_runtime.h>
#include <cstdint>

#define K_NE 16
constexpr int B = 8, N = 2048, F = 128;
constexpr size_t NSEND = (size_t)B * N;                 // 16384 sender rows
constexpr size_t EDGE_FLOATS = NSEND * K_NE * 256;      // 67,108,864
constexpr size_t SEND_FLOATS = (size_t)B * N * N;       // 33,554,432

// ---------------- K0: row norms (one wave per 128-float row) ----------------
__global__ __launch_bounds__(256) void norms_kernel(const float* __restrict__ X,
                                                    float* __restrict__ out) {
    int tid = blockIdx.x * 256 + threadIdx.x;
    int w = tid >> 6, lane = tid & 63;
    const float2 v = ((const float2*)(X + (size_t)w * F))[lane];
    float s = v.x * v.x + v.y * v.y;
    #pragma unroll
    for (int off = 32; off; off >>= 1) s += __shfl_xor(s, off);
    if (lane == 0) out[w] = s;
}

// ---------------- K1: score matrix  dist[b][s][r] = |x2+y2-2*dot| -----------
// 128x128 block tile, 256 threads, 8x8 micro-tile (2x2 of float4),
// K-major LDS [BK=8][128] so fragment reads are conflict-free (2-way max).
__global__ __launch_bounds__(256) void score_kernel(const float* __restrict__ S,
                                                    const float* __restrict__ Rv,
                                                    const float* __restrict__ x2,
                                                    const float* __restrict__ y2,
                                                    float* __restrict__ scores) {
    __shared__ float As[8][128];   // [k][row]  (A = senders)
    __shared__ float Bs[8][128];   // [k][col]  (B = receivers)
    const int bx = blockIdx.x, by = blockIdx.y, bz = blockIdx.z;
    const int t = threadIdx.x;
    const int tx = t & 15, ty = t >> 4;          // 16x16 thread grid
    const float* Sb = S  + (size_t)bz * N * F + (size_t)by * 128 * F;
    const float* Rb = Rv + (size_t)bz * N * F + (size_t)bx * 128 * F;

    // staging role: each thread loads one float4 of A and one of B per chunk
    const int srow = t >> 1;            // 0..127
    const int skq  = (t & 1) << 2;      // 0 or 4 (k-quad within BK=8)

    float acc[8][8] = {};   // row i: ty*4+(i&3)+64*(i>>2); col j: tx*4+(j&3)+64*(j>>2)

    for (int kc = 0; kc < 16; ++kc) {   // 16 chunks of BK=8 over K=128
        const float4 a = *(const float4*)(Sb + (size_t)srow * F + (kc << 3) + skq);
        const float4 b = *(const float4*)(Rb + (size_t)srow * F + (kc << 3) + skq);
        __syncthreads();   // previous chunk's reads done before overwrite
        As[skq + 0][srow] = a.x; As[skq + 1][srow] = a.y;
        As[skq + 2][srow] = a.z; As[skq + 3][srow] = a.w;
        Bs[skq + 0][srow] = b.x; Bs[skq + 1][srow] = b.y;
        Bs[skq + 2][srow] = b.z; Bs[skq + 3][srow] = b.w;
        __syncthreads();
        #pragma unroll
        for (int k = 0; k < 8; ++k) {
            float4 a0 = *(const float4*)(&As[k][ty * 4]);
            float4 a1 = *(const float4*)(&As[k][64 + ty * 4]);
            float4 b0 = *(const float4*)(&Bs[k][tx * 4]);
            float4 b1 = *(const float4*)(&Bs[k][64 + tx * 4]);
            float av[8] = {a0.x, a0.y, a0.z, a0.w, a1.x, a1.y, a1.z, a1.w};
            float bv[8] = {b0.x, b0.y, b0.z, b0.w, b1.x, b1.y, b1.z, b1.w};
            #pragma unroll
            for (int i = 0; i < 8; ++i)
                #pragma unroll
                for (int j = 0; j < 8; ++j)
                    acc[i][j] = fmaf(av[i], bv[j], acc[i][j]);
        }
    }

    float* outb = scores + (size_t)bz * N * N;
    const float* x2b = x2 + (size_t)bz * N;
    const float* y2b = y2 + (size_t)bz * N;
    float yv[8];
    #pragma unroll
    for (int c = 0; c < 4; ++c) {
        yv[c]     = y2b[bx * 128 + tx * 4 + c];
        yv[4 + c] = y2b[bx * 128 + 64 + tx * 4 + c];
    }
    #pragma unroll
    for (int i = 0; i < 8; ++i) {
        const int r = by * 128 + ty * 4 + (i & 3) + 64 * (i >> 2);
        const float xv = x2b[r];
        float* orow = outb + (size_t)r * N + bx * 128;
        float4 o0, o1;
        o0.x = fabsf((-2.0f * acc[i][0] + xv) + yv[0]);
        o0.y = fabsf((-2.0f * acc[i][1] + xv) + yv[1]);
        o0.z = fabsf((-2.0f * acc[i][2] + xv) + yv[2]);
        o0.w = fabsf((-2.0f * acc[i][3] + xv) + yv[3]);
        o1.x = fabsf((-2.0f * acc[i][4] + xv) + yv[4]);
        o1.y = fabsf((-2.0f * acc[i][5] + xv) + yv[5]);
        o1.z = fabsf((-2.0f * acc[i][6] + xv) + yv[6]);
        o1.w = fabsf((-2.0f * acc[i][7] + xv) + yv[7]);
        *(float4*)(orow + tx * 4)      = o0;
        *(float4*)(orow + 64 + tx * 4) = o1;
    }
}

// ---------------- K2: top-16 per sender row, ascending-index emit -----------
__global__ __launch_bounds__(256) void topk_kernel(const float* __restrict__ scores,
                                                   int* __restrict__ idxb) {
    const int t = threadIdx.x;
    const int lane = t & 63;
    const int row = blockIdx.x * 4 + (t >> 6);   // global sender id
    const float* sr = scores + (size_t)row * N;
    float c[32], w[32];
    #pragma unroll
    for (int j = 0; j < 32; ++j) { c[j] = sr[(j << 6) + lane]; w[j] = c[j]; }
    float T = 0.0f;
    for (int it = 0; it < 16; ++it) {
        float bv = w[0]; int bi = lane;
        #pragma unroll
        for (int j = 1; j < 32; ++j) {
            int idx = (j << 6) + lane;
            if (w[j] < bv) { bv = w[j]; bi = idx; }
        }
        #pragma unroll
        for (int off = 32; off; off >>= 1) {
            float ov = __shfl_xor(bv, off);
            int   oi = __shfl_xor(bi, off);
            if (ov < bv || (ov == bv && oi < bi)) { bv = ov; bi = oi; }
        }
        T = bv;
        int jj = bi >> 6;
        bool mine = (bi & 63) == lane;
        #pragma unroll
        for (int j = 0; j < 32; ++j)
            if (mine && jj == j) w[j] = __builtin_inff();
    }
    int m = 0;
    #pragma unroll
    for (int j = 0; j < 32; ++j) m += __popcll(__ballot(c[j] < T));
    const int quota = K_NE - m;
    const unsigned long long lt = (1ull << lane) - 1ull;
    int emitted = 0, eqc = 0;
    int* ob = idxb + row * K_NE;
    #pragma unroll
    for (int j = 0; j < 32; ++j) {
        float v = c[j];
        int idx = (j << 6) + lane;
        unsigned long long em = __ballot(v == T);
        int eq_rank = eqc + __popcll(em & lt);
        bool acc = (v < T) || ((v == T) && (eq_rank < quota));
        unsigned long long am = __ballot(acc);
        if (acc) ob[emitted + __popcll(am & lt)] = idx;
        emitted += __popcll(am);
        eqc += __popcll(em);
    }
}

// ---------------- K3: edge rows (fully coalesced float4 writes) -------------
__global__ __launch_bounds__(256) void edges_kernel(const float* __restrict__ S,
                                                    const float* __restrict__ Rv,
                                                    const int* __restrict__ idxb,
                                                    float* __restrict__ out) {
    const int g = blockIdx.x;            // sender id 0..16383
    const int t = threadIdx.x;
    __shared__ int sidx[K_NE];
    if (t < K_NE) sidx[t] = idxb[g * K_NE + t];
    __syncthreads();
    const float4* srow = (const float4*)(S + (size_t)g * F);
    const float4* rb = (const float4*)(Rv + (size_t)(g >> 11) * N * F);
    float4* ob = (float4*)(out + (size_t)g * (K_NE * 256));
    #pragma unroll
    for (int i = 0; i < 4; ++i) {
        int f = t + (i << 8);            // float4 id within the 16x256 block
        int e = f >> 6, p = f & 63;
        float4 v = (p < 32) ? srow[p] : rb[(size_t)sidx[e] * 32 + (p - 32)];
        ob[f] = v;
    }
}

// ---------------- K4: scatter ones into zeroed connectivity matrix ----------
__global__ __launch_bounds__(256) void ones_kernel(const int* __restrict__ idxb,
                                                   float* __restrict__ sm) {
    int e = blockIdx.x * 256 + threadIdx.x;  // edge id 0..262143
    int g = e >> 4;
    int col = idxb[e];
    sm[(size_t)g * N + col] = 1.0f;
}

extern "C" void kernel_launch(void* const* d_in, const int* in_sizes, int n_in,
                              void* d_out, int out_size, void* d_ws, size_t ws_size,
                              hipStream_t stream) {
    (void)in_sizes; (void)n_in; (void)out_size;
    const float* recv = (const float*)d_in[0];
    const float* send = (const float*)d_in[1];
    float* out = (float*)d_out;
    float* sender_mat = out + EDGE_FLOATS;       // also used as 128MB score scratch
    int*   idx_ws = (int*)d_ws;
    float* x2 = (float*)((char*)d_ws + (262144u * 4));
    float* y2 = x2 + NSEND;

    norms_kernel<<<4096, 256, 0, stream>>>(send, x2);
    norms_kernel<<<4096, 256, 0, stream>>>(recv, y2);
    dim3 g1(16, 16, 8);
    score_kernel<<<g1, 256, 0, stream>>>(send, recv, x2, y2, sender_mat);
    topk_kernel<<<4096, 256, 0, stream>>>(sender_mat, idx_ws);
    edges_kernel<<<16384, 256, 0, stream>>>(send, recv, idx_ws, out);
    hipMemsetAsync(sender_mat, 0, SEND_FLOATS * sizeof(float), stream);
    ones_kernel<<<1024, 256, 0, stream>>>(idx_ws, sender_mat);
}